// Round 6
// baseline (1314.966 us; speedup 1.0000x reference)
//
#include <hip/hip_runtime.h>
#include <stdint.h>

#define TB 256

// ---------------- marching-tets tables ----------------
static __device__ __constant__ int d_TRI[16][6] = {
  {-1,-1,-1,-1,-1,-1},{1,0,2,-1,-1,-1},{4,0,3,-1,-1,-1},{1,4,2,1,3,4},
  {3,1,5,-1,-1,-1},{2,3,0,2,5,3},{1,4,0,1,5,4},{4,2,5,-1,-1,-1},
  {4,5,2,-1,-1,-1},{4,1,0,4,5,1},{3,2,0,3,5,2},{1,3,5,-1,-1,-1},
  {4,1,2,4,3,1},{3,0,4,-1,-1,-1},{2,0,1,-1,-1,-1},{-1,-1,-1,-1,-1,-1}};
static __device__ __constant__ int d_NT[16] = {0,1,1,2,1,2,2,1,1,2,2,1,2,1,1,0};
static __device__ __constant__ int d_EA[6] = {0,0,0,1,1,2};
static __device__ __constant__ int d_EB[6] = {1,2,3,2,3,3};

__device__ __forceinline__ void wave_sync_lds() {
  __builtin_amdgcn_sched_barrier(0);
  asm volatile("s_waitcnt lgkmcnt(0)" ::: "memory");
  __builtin_amdgcn_sched_barrier(0);
}

// ---------------- scan (exclusive, u32, out has n+1 entries) ----------------
#define SB 256
#define SI 8
#define STILE (SB*SI)

__global__ void k_scan_partial(const unsigned* __restrict__ in, unsigned* __restrict__ bsum, int n) {
  int b = blockIdx.x;
  int base = b * STILE;
  __shared__ unsigned sh[SB];
  unsigned s = 0;
  for (int i = threadIdx.x; i < STILE; i += SB) {
    int idx = base + i;
    s += (idx < n) ? in[idx] : 0u;
  }
  sh[threadIdx.x] = s; __syncthreads();
  for (int st = SB/2; st > 0; st >>= 1) {
    if (threadIdx.x < st) sh[threadIdx.x] += sh[threadIdx.x + st];
    __syncthreads();
  }
  if (threadIdx.x == 0) bsum[b] = sh[0];
}

__global__ void k_scan_mid(const unsigned* __restrict__ bsum, unsigned* __restrict__ boff,
                           int B, unsigned* __restrict__ total_dst) {
  int t = threadIdx.x;
  unsigned loc[SI];
  int base = t * SI;
  unsigned s = 0;
  #pragma unroll
  for (int i = 0; i < SI; ++i) {
    int idx = base + i;
    unsigned v = (idx < B) ? bsum[idx] : 0u;
    loc[i] = s; s += v;
  }
  __shared__ unsigned sh[SB];
  sh[t] = s; __syncthreads();
  for (int o = 1; o < SB; o <<= 1) {
    unsigned v = (t >= o) ? sh[t - o] : 0u;
    __syncthreads();
    sh[t] += v;
    __syncthreads();
  }
  unsigned texcl = sh[t] - s;
  #pragma unroll
  for (int i = 0; i < SI; ++i) {
    int idx = base + i;
    if (idx < B) boff[idx] = texcl + loc[i];
  }
  if (t == SB - 1 && total_dst) *total_dst = sh[SB - 1];
}

__global__ void k_scan_final(const unsigned* __restrict__ in, const unsigned* __restrict__ boff,
                             unsigned* __restrict__ out, int n) {
  int b = blockIdx.x;
  int base = b * STILE + threadIdx.x * SI;
  unsigned loc[SI];
  unsigned s = 0;
  #pragma unroll
  for (int i = 0; i < SI; ++i) {
    int idx = base + i;
    unsigned v = (idx < n) ? in[idx] : 0u;
    loc[i] = s; s += v;
  }
  __shared__ unsigned sh[SB];
  int t = threadIdx.x;
  sh[t] = s; __syncthreads();
  for (int o = 1; o < SB; o <<= 1) {
    unsigned v = (t >= o) ? sh[t - o] : 0u;
    __syncthreads();
    sh[t] += v;
    __syncthreads();
  }
  unsigned texcl = sh[t] - s;
  unsigned bo = boff[b];
  #pragma unroll
  for (int i = 0; i < SI; ++i) {
    int idx = base + i;
    if (idx < n) out[idx] = bo + texcl + loc[i];
  }
}

// ---------------- pipeline kernels ----------------

// classification: occ byte, fine histogram (lo>>6), per-block tri sums
__global__ void k_classify(const int* __restrict__ tet, const float* __restrict__ sdf,
                           unsigned* __restrict__ fineCnt, unsigned char* __restrict__ occb,
                           unsigned* __restrict__ bs, int F, int FB) {
  int f = blockIdx.x * TB + threadIdx.x;
  unsigned pk = 0;
  if (f < F) {
    int4 q = reinterpret_cast<const int4*>(tet)[f];
    int v[4] = {q.x, q.y, q.z, q.w};
    int oc[4];
    #pragma unroll
    for (int i = 0; i < 4; ++i) oc[i] = sdf[v[i]] > 0.0f;
    int tix = oc[0] | (oc[1] << 1) | (oc[2] << 2) | (oc[3] << 3);
    occb[f] = (unsigned char)tix;
    int nt = d_NT[tix];
    pk = (nt == 1 ? 1u : 0u) | (nt == 2 ? 0x10000u : 0u);
    if (nt > 0) {
      #pragma unroll
      for (int e = 0; e < 6; ++e) {
        int ai = d_EA[e], bi = d_EB[e];
        if (oc[ai] != oc[bi]) {
          int a = v[ai], b = v[bi];
          int lo = a < b ? a : b;
          atomicAdd(&fineCnt[lo >> 6], 1u);
        }
      }
    }
  }
  __shared__ unsigned sh[TB];
  sh[threadIdx.x] = pk; __syncthreads();
  for (int st = TB/2; st > 0; st >>= 1) {
    if (threadIdx.x < st) sh[threadIdx.x] += sh[threadIdx.x + st];
    __syncthreads();
  }
  if (threadIdx.x == 0) {
    unsigned t = sh[0];
    bs[blockIdx.x] = t & 0xFFFFu;
    bs[FB + blockIdx.x] = t >> 16;
  }
}

// init cursors after fine scan
__global__ void k_init(const unsigned* __restrict__ fineOff, unsigned* __restrict__ finecur,
                       unsigned* __restrict__ ccur, int PF, int PC) {
  int i = blockIdx.x * TB + threadIdx.x;
  if (i < PF) finecur[i] = fineOff[i];
  if (i < 64) ccur[i] = (i < PC) ? fineOff[i * 128] : 0u;
}

// pass 1: LDS-binned scatter into <=37 coarse partitions (lo>>13); coalesced run flushes
#define P1MAX 1536
__global__ void k_scat1(const int* __restrict__ tet, const unsigned char* __restrict__ occb,
                        unsigned* __restrict__ ccur, unsigned* __restrict__ streamA,
                        int F, unsigned capA) {
  __shared__ unsigned hist[64], offb[64], cur[64], gb[64];
  __shared__ unsigned sbuf[P1MAX];
  __shared__ unsigned char sfb[P1MAX];
  int t = threadIdx.x;
  if (t < 64) { hist[t] = 0; cur[t] = 0; }
  __syncthreads();
  int f = blockIdx.x * TB + t;
  unsigned ev[6]; unsigned char fv[6]; unsigned vm = 0;
  #pragma unroll
  for (int e = 0; e < 6; ++e) { ev[e] = 0; fv[e] = 0; }
  if (f < F) {
    int tix = occb[f];
    if (tix != 0 && tix != 15) {
      int4 q = reinterpret_cast<const int4*>(tet)[f];
      int v[4] = {q.x, q.y, q.z, q.w};
      #pragma unroll
      for (int e = 0; e < 6; ++e) {
        int ai = d_EA[e], bi = d_EB[e];
        if (((tix >> ai) & 1) != ((tix >> bi) & 1)) {
          int a = v[ai], b = v[bi];
          int lo = a < b ? a : b;
          int hi = a < b ? b : a;
          ev[e] = ((unsigned)(lo & 8191) << 19) | (unsigned)hi;
          fv[e] = (unsigned char)(lo >> 13);
          atomicAdd(&hist[lo >> 13], 1u);
          vm |= 1u << e;
        }
      }
    }
  }
  __syncthreads();
  if (t == 0) { unsigned s = 0; for (int i = 0; i < 64; ++i) { offb[i] = s; s += hist[i]; } }
  __syncthreads();
  #pragma unroll
  for (int e = 0; e < 6; ++e) if ((vm >> e) & 1) {
    unsigned fb = fv[e];
    unsigned slot = offb[fb] + atomicAdd(&cur[fb], 1u);
    if (slot < P1MAX) { sbuf[slot] = ev[e]; sfb[slot] = (unsigned char)fb; }
  }
  if (t < 64 && hist[t] > 0) gb[t] = atomicAdd(&ccur[t], hist[t]);
  __syncthreads();
  unsigned total = offb[63] + hist[63];
  if (total > P1MAX) total = P1MAX;
  for (unsigned i = t; i < total; i += TB) {
    unsigned fb = sfb[i];
    unsigned pos = gb[fb] + (i - offb[fb]);
    if (pos < capA) streamA[pos] = sbuf[i];
  }
}

// pass 2: repartition coarse -> fine (128 bins of 64 lo each); coalesced run flushes.
// NPB=64: worst coarse partition (~242K entries, lo-min skew 2x at 0) -> chunk <= ~3790 < P2CAP.
#define NPB 64
#define P2CAP 4096
__global__ void k_repart(const unsigned* __restrict__ fineOff, const unsigned* __restrict__ streamA,
                         unsigned* __restrict__ finecur, unsigned* __restrict__ streamB,
                         int PF, unsigned capB) {
  __shared__ unsigned hist[128], offb[128], cur[128], gb[128];
  __shared__ unsigned sorted[P2CAP];
  __shared__ unsigned char sfb[P2CAP];
  int t = threadIdx.x;
  int pc = blockIdx.x / NPB;
  int ib = blockIdx.x % NPB;
  for (int i = t; i < 128; i += TB) { hist[i] = 0; cur[i] = 0; }
  __syncthreads();
  int fs = pc * 128;
  int fe = fs + 128; if (fe > PF) fe = PF;
  unsigned base = fineOff[fs], end = fineOff[fe];
  unsigned cc = end - base;
  unsigned chunk = (cc + NPB - 1) / NPB;
  if (chunk > P2CAP) chunk = P2CAP;   // safety (should never trigger at NPB=64)
  unsigned s = base + (unsigned)ib * chunk;
  if (s > end) s = end;
  unsigned e_ = s + chunk; if (e_ > end) e_ = end;
  unsigned ev[16]; unsigned char fv[16];
  #pragma unroll
  for (int j = 0; j < 16; ++j) {
    unsigned idx = s + (unsigned)(j * TB) + (unsigned)t;
    bool ok = idx < e_;
    unsigned eV = 0;
    if (ok) { eV = streamA[idx]; atomicAdd(&hist[eV >> 25], 1u); }
    ev[j] = eV; fv[j] = ok ? (unsigned char)(eV >> 25) : (unsigned char)255;
  }
  __syncthreads();
  if (t == 0) { unsigned ss = 0; for (int i = 0; i < 128; ++i) { offb[i] = ss; ss += hist[i]; } }
  __syncthreads();
  #pragma unroll
  for (int j = 0; j < 16; ++j) if (fv[j] != 255) {
    unsigned fb = fv[j];
    unsigned slot = offb[fb] + atomicAdd(&cur[fb], 1u);
    if (slot < P2CAP) { sorted[slot] = ev[j] & 0x1FFFFFFu; sfb[slot] = fv[j]; }
  }
  if (t < 128 && hist[t] > 0) gb[t] = atomicAdd(&finecur[fs + t], hist[t]);
  __syncthreads();
  unsigned total = offb[127] + hist[127];
  if (total > P2CAP) total = P2CAP;
  for (unsigned i = t; i < total; i += TB) {
    unsigned fb = sfb[i];
    unsigned pos = gb[fb] + (i - offb[fb]);
    if (pos < capB) streamB[pos] = sorted[i];
  }
}

// one 512-thread block per fine partition (64 lo); 8 waves each sort+dedupe one 8-lo bucket.
// PCAP=2560: partition 0 expects ~1920 entries (lo-min skew), +14 sigma margin.
#define PCAP 2560
#define CAP 512
__global__ void __launch_bounds__(512) k_sortdd(
    const unsigned* __restrict__ fineOff, unsigned* __restrict__ streamB,
    unsigned* __restrict__ ucnt, unsigned* __restrict__ ucC,
    unsigned* __restrict__ ustart, int N) {
  __shared__ unsigned sSt[PCAP];
  __shared__ unsigned sA[8][CAP];
  __shared__ unsigned sD[8][CAP];
  __shared__ unsigned sUc[8];
  int t = threadIdx.x;
  int w = t >> 6, lane = t & 63;
  int fp = blockIdx.x;
  unsigned base = fineOff[fp];
  unsigned n = fineOff[fp + 1] - base;
  if (n > PCAP) n = PCAP;   // safety (should never trigger at PCAP=2560)
  for (unsigned k = t; k < n; k += 512) sSt[k] = streamB[base + k];
  __syncthreads();
  // filter this wave's 8-lo bucket ((e>>22)&7 == w) into sA[w]
  unsigned nw = 0;
  for (unsigned c = 0; c < n; c += 64) {
    unsigned j = c + (unsigned)lane; bool m = false; unsigned e = 0;
    if (j < n) { e = sSt[j]; m = ((e >> 22) & 7u) == (unsigned)w; }
    unsigned long long bal = __ballot((int)m);
    if (m) {
      unsigned pos = nw + (unsigned)__popcll(bal & ((1ull << lane) - 1ull));
      if (pos < CAP) sA[w][pos] = e;
    }
    nw += (unsigned)__popcll(bal);
  }
  if (nw > CAP) nw = CAP;   // safety
  wave_sync_lds();
  // rank-sort sA[w][0..nw) -> sD[w]
  for (unsigned k = lane; k < nw; k += 64) {
    unsigned val = sA[w][k];
    unsigned r = 0;
    for (unsigned j = 0; j < nw; ++j) {
      unsigned x = sA[w][j];
      r += (x < val) || (x == val && j < k);
    }
    sD[w][r] = val;
  }
  wave_sync_lds();
  // dedupe sD -> sA
  unsigned ub = 0;
  for (unsigned c = 0; c < nw; c += 64) {
    unsigned k = c + (unsigned)lane;
    bool act = k < nw;
    unsigned val = act ? sD[w][k] : 0u;
    bool flag = act && (k == 0 || val != sD[w][k - 1]);
    unsigned long long m2 = __ballot((int)flag);
    if (flag) {
      unsigned pos = ub + (unsigned)__popcll(m2 & ((1ull << lane) - 1ull));
      sA[w][pos] = val;
    }
    ub += (unsigned)__popcll(m2);
  }
  wave_sync_lds();
  if (lane == 0) sUc[w] = ub;
  __syncthreads();
  unsigned pre = 0;
  for (int i = 0; i < w; ++i) pre += sUc[i];
  unsigned ust = base + pre;
  // write packed uniques (idx<<25 | lo6<<19 | hi) back into streamB (reads were from sSt)
  for (unsigned k = lane; k < ub; k += 64) {
    unsigned e = sA[w][k];
    unsigned j = k;
    while (j > 0 && (sA[w][j - 1] >> 19) == (e >> 19)) --j;
    streamB[ust + k] = ((k - j) << 25) | e;
  }
  // per-lo unique counts
  if (lane < 8) {
    unsigned c = 0;
    for (unsigned j = 0; j < ub; ++j) c += ((sA[w][j] >> 19) & 7u) == (unsigned)lane;
    int lo = fp * 64 + w * 8 + (int)lane;
    if (lo < N) ucnt[lo] = c;
  }
  int cb = fp * 8 + w;
  if (lane == 0) { ucC[cb] = ub; ustart[cb] = ust; }
}

// verts + uniq table (uniq table lives in streamA, dead after repart)
__global__ void k_verts(const unsigned* __restrict__ ustart, const unsigned* __restrict__ ucC,
                        const unsigned* __restrict__ uoff, const unsigned* __restrict__ streamB,
                        unsigned* __restrict__ uniqA, const float* __restrict__ pos,
                        const float* __restrict__ sdf, float* __restrict__ out,
                        int NCB, int N, unsigned out_cap) {
  int w = threadIdx.x >> 6, lane = threadIdx.x & 63;
  int cb = blockIdx.x * 4 + w;
  if (cb >= NCB) return;
  unsigned u = ucC[cb];
  if (u == 0) return;
  unsigned us = ustart[cb];
  unsigned lobase = (unsigned)(cb >> 3) * 64u;
  unsigned M = uoff[N];
  for (unsigned k = lane; k < u; k += 64) {
    unsigned e = streamB[us + k];
    unsigned hi = e & 0x7FFFFu;
    unsigned lo = lobase + ((e >> 19) & 63u);
    unsigned idx = e >> 25;
    if (lo >= (unsigned)N || hi >= (unsigned)N) continue;
    unsigned r = uoff[lo] + idx;
    if (r >= M) continue;
    size_t ro = (size_t)3 * r;
    if (ro + 3 > (size_t)out_cap) continue;
    uniqA[r] = hi;
    float a = sdf[lo], b = sdf[hi];
    float d = a - b;
    float w0 = -b / d;
    float w1 = a / d;
    out[ro + 0] = pos[3 * (size_t)lo + 0] * w0 + pos[3 * (size_t)hi + 0] * w1;
    out[ro + 1] = pos[3 * (size_t)lo + 1] * w0 + pos[3 * (size_t)hi + 1] * w1;
    out[ro + 2] = pos[3 * (size_t)lo + 2] * w0 + pos[3 * (size_t)hi + 2] * w1;
  }
}

// faces: block-local scan + per-block offsets from C over [bs1|bs2]; bounded uniq search
__global__ void k_faces(const int* __restrict__ tet, const unsigned char* __restrict__ occb,
                        const unsigned* __restrict__ uoff, const unsigned* __restrict__ uniqA,
                        const unsigned* __restrict__ C, float* __restrict__ out,
                        int F, int FB, int N, unsigned out_cap) {
  int f = blockIdx.x * TB + threadIdx.x;
  int tix = (f < F) ? (int)occb[f] : 0;
  int nt = d_NT[tix];
  unsigned pk = (nt == 1 ? 1u : 0u) | (nt == 2 ? 0x10000u : 0u);
  __shared__ unsigned sh[TB];
  int t = threadIdx.x;
  sh[t] = pk; __syncthreads();
  for (int o = 1; o < TB; o <<= 1) {
    unsigned v = (t >= o) ? sh[t - o] : 0u;
    __syncthreads();
    sh[t] += v;
    __syncthreads();
  }
  unsigned excl = sh[t] - pk;
  if (f >= F || nt == 0) return;
  unsigned C1b = C[blockIdx.x];
  unsigned T1 = C[FB];
  unsigned C2b = C[FB + blockIdx.x] - T1;
  unsigned M = uoff[N];
  int4 q = reinterpret_cast<const int4*>(tet)[f];
  int v[4] = {q.x, q.y, q.z, q.w};
  int rank[6];
  #pragma unroll
  for (int e = 0; e < 6; ++e) {
    int ai = d_EA[e], bi = d_EB[e];
    int oa = (tix >> ai) & 1, ob = (tix >> bi) & 1;
    if (oa != ob) {
      int a = v[ai], b = v[bi];
      int lo = a < b ? a : b;
      int hi = a < b ? b : a;
      unsigned ubase = uoff[lo];
      unsigned len = uoff[lo + 1] - ubase;   // bounded search — no hang possible
      unsigned rk = ubase;
      for (unsigned j = 0; j < len; ++j) {
        if (uniqA[ubase + j] == (unsigned)hi) { rk = ubase + j; break; }
      }
      rank[e] = (int)rk;
    } else {
      rank[e] = -1;
    }
  }
  const int* tt = d_TRI[tix];
  if (nt == 1) {
    unsigned r = C1b + (excl & 0xFFFFu);
    size_t o = (size_t)3 * M + (size_t)3 * r;
    if (o + 3 <= (size_t)out_cap) {
      out[o + 0] = (float)rank[tt[0]];
      out[o + 1] = (float)rank[tt[1]];
      out[o + 2] = (float)rank[tt[2]];
    }
  } else {
    unsigned r0 = T1 + 2u * (C2b + (excl >> 16));
    size_t o = (size_t)3 * M + (size_t)3 * r0;
    if (o + 6 <= (size_t)out_cap) {
      #pragma unroll
      for (int c = 0; c < 6; ++c) out[o + c] = (float)rank[tt[c]];
    }
  }
}

// ---------------- host launcher ----------------
static void run_scan(const unsigned* in, unsigned* out, int n,
                     unsigned* bsum, unsigned* boff, hipStream_t s) {
  int B = (n + STILE - 1) / STILE;
  k_scan_partial<<<B, SB, 0, s>>>(in, bsum, n);
  k_scan_mid<<<1, SB, 0, s>>>(bsum, boff, B, out + n);
  k_scan_final<<<B, SB, 0, s>>>(in, boff, out, n);
}

extern "C" void kernel_launch(void* const* d_in, const int* in_sizes, int n_in,
                              void* d_out, int out_size, void* d_ws, size_t ws_size,
                              hipStream_t stream) {
  const float* pos = (const float*)d_in[0];
  const float* sdf = (const float*)d_in[1];
  const int* tet = (const int*)d_in[2];
  int N = in_sizes[1];
  int F = in_sizes[2] / 4;
  float* out = (float*)d_out;

  char* w = (char*)d_ws;
  size_t o = 0;
  auto take = [&](size_t bytes) -> char* {
    char* p = w + o;
    o = (o + bytes + 255) & ~(size_t)255;
    return p;
  };
  int FB = (F + TB - 1) / TB;
  int PF = (N + 63) / 64;          // fine partitions (64 lo each)
  int PC = (PF + 127) / 128;       // coarse partitions (8192 lo each)
  int NCB = PF * 8;                // 8-lo buckets
  unsigned capS = (unsigned)(4 * F);   // stream capacity in entries

  unsigned* fineCnt = (unsigned*)take((size_t)(PF + 1) * 4);
  unsigned* fineOff = (unsigned*)take((size_t)(PF + 1) * 4);
  unsigned* finecur = (unsigned*)take((size_t)(PF + 1) * 4);
  unsigned* ccur    = (unsigned*)take(64 * 4);
  unsigned* ucnt    = (unsigned*)take((size_t)(N + 1) * 4);
  unsigned* uoff    = (unsigned*)take((size_t)(N + 1) * 4);
  unsigned* ucC     = (unsigned*)take((size_t)NCB * 4);
  unsigned* ustart  = (unsigned*)take((size_t)NCB * 4);
  unsigned* bs      = (unsigned*)take((size_t)2 * FB * 4);
  unsigned* C       = (unsigned*)take(((size_t)2 * FB + 1) * 4);
  unsigned char* occb = (unsigned char*)take((size_t)F);
  unsigned* streamA = (unsigned*)take((size_t)capS * 4);  // coarse stream, later uniq table
  unsigned* streamB = (unsigned*)take((size_t)capS * 4);  // fine stream, later packed uniques
  unsigned* bsum    = (unsigned*)take(4096 * 4);
  unsigned* boff    = (unsigned*)take(4096 * 4);

  // 1) zero fine histogram
  hipMemsetAsync(fineCnt, 0, (size_t)(PF + 1) * 4, stream);
  // 2) classify
  k_classify<<<FB, TB, 0, stream>>>(tet, sdf, fineCnt, occb, bs, F, FB);
  // 3) fine offsets
  run_scan(fineCnt, fineOff, PF, bsum, boff, stream);
  // 4) cursors
  k_init<<<(PF + TB - 1) / TB, TB, 0, stream>>>(fineOff, finecur, ccur, PF, PC);
  // 5) coarse binned scatter
  k_scat1<<<FB, TB, 0, stream>>>(tet, occb, ccur, streamA, F, capS);
  // 6) repartition coarse -> fine
  k_repart<<<PC * NPB, TB, 0, stream>>>(fineOff, streamA, finecur, streamB, PF, capS);
  // 7) per-fine-partition sort + dedupe (uniques back into streamB)
  k_sortdd<<<PF, 512, 0, stream>>>(fineOff, streamB, ucnt, ucC, ustart, N);
  // 8) unique offsets (global lex ranks); uoff[N] = M
  run_scan(ucnt, uoff, N, bsum, boff, stream);
  // 9) verts + uniq table (into streamA)
  k_verts<<<(NCB + 3) / 4, TB, 0, stream>>>(ustart, ucC, uoff, streamB, streamA,
                                            pos, sdf, out, NCB, N, (unsigned)out_size);
  // 10) face row offsets
  run_scan(bs, C, 2 * FB, bsum, boff, stream);
  // 11) faces
  k_faces<<<FB, TB, 0, stream>>>(tet, occb, uoff, streamA, C, out, F, FB, N, (unsigned)out_size);
}

// Round 7
// 974.635 us; speedup vs baseline: 1.3492x; 1.3492x over previous
//
#include <hip/hip_runtime.h>
#include <stdint.h>

#define TB 256

// ---------------- marching-tets tables ----------------
static __device__ __constant__ int d_TRI[16][6] = {
  {-1,-1,-1,-1,-1,-1},{1,0,2,-1,-1,-1},{4,0,3,-1,-1,-1},{1,4,2,1,3,4},
  {3,1,5,-1,-1,-1},{2,3,0,2,5,3},{1,4,0,1,5,4},{4,2,5,-1,-1,-1},
  {4,5,2,-1,-1,-1},{4,1,0,4,5,1},{3,2,0,3,5,2},{1,3,5,-1,-1,-1},
  {4,1,2,4,3,1},{3,0,4,-1,-1,-1},{2,0,1,-1,-1,-1},{-1,-1,-1,-1,-1,-1}};
static __device__ __constant__ int d_NT[16] = {0,1,1,2,1,2,2,1,1,2,2,1,2,1,1,0};
static __device__ __constant__ int d_EA[6] = {0,0,0,1,1,2};
static __device__ __constant__ int d_EB[6] = {1,2,3,2,3,3};

__device__ __forceinline__ void wave_sync_lds() {
  __builtin_amdgcn_sched_barrier(0);
  asm volatile("s_waitcnt lgkmcnt(0)" ::: "memory");
  __builtin_amdgcn_sched_barrier(0);
}

// ---------------- scan (exclusive, u32, out has n+1 entries) ----------------
#define SB 256
#define SI 8
#define STILE (SB*SI)

__global__ void k_scan_partial(const unsigned* __restrict__ in, unsigned* __restrict__ bsum, int n) {
  int b = blockIdx.x;
  int base = b * STILE;
  __shared__ unsigned sh[SB];
  unsigned s = 0;
  for (int i = threadIdx.x; i < STILE; i += SB) {
    int idx = base + i;
    s += (idx < n) ? in[idx] : 0u;
  }
  sh[threadIdx.x] = s; __syncthreads();
  for (int st = SB/2; st > 0; st >>= 1) {
    if (threadIdx.x < st) sh[threadIdx.x] += sh[threadIdx.x + st];
    __syncthreads();
  }
  if (threadIdx.x == 0) bsum[b] = sh[0];
}

__global__ void k_scan_mid(const unsigned* __restrict__ bsum, unsigned* __restrict__ boff,
                           int B, unsigned* __restrict__ total_dst) {
  int t = threadIdx.x;
  unsigned loc[SI];
  int base = t * SI;
  unsigned s = 0;
  #pragma unroll
  for (int i = 0; i < SI; ++i) {
    int idx = base + i;
    unsigned v = (idx < B) ? bsum[idx] : 0u;
    loc[i] = s; s += v;
  }
  __shared__ unsigned sh[SB];
  sh[t] = s; __syncthreads();
  for (int o = 1; o < SB; o <<= 1) {
    unsigned v = (t >= o) ? sh[t - o] : 0u;
    __syncthreads();
    sh[t] += v;
    __syncthreads();
  }
  unsigned texcl = sh[t] - s;
  #pragma unroll
  for (int i = 0; i < SI; ++i) {
    int idx = base + i;
    if (idx < B) boff[idx] = texcl + loc[i];
  }
  if (t == SB - 1 && total_dst) *total_dst = sh[SB - 1];
}

__global__ void k_scan_final(const unsigned* __restrict__ in, const unsigned* __restrict__ boff,
                             unsigned* __restrict__ out, int n) {
  int b = blockIdx.x;
  int base = b * STILE + threadIdx.x * SI;
  unsigned loc[SI];
  unsigned s = 0;
  #pragma unroll
  for (int i = 0; i < SI; ++i) {
    int idx = base + i;
    unsigned v = (idx < n) ? in[idx] : 0u;
    loc[i] = s; s += v;
  }
  __shared__ unsigned sh[SB];
  int t = threadIdx.x;
  sh[t] = s; __syncthreads();
  for (int o = 1; o < SB; o <<= 1) {
    unsigned v = (t >= o) ? sh[t - o] : 0u;
    __syncthreads();
    sh[t] += v;
    __syncthreads();
  }
  unsigned texcl = sh[t] - s;
  unsigned bo = boff[b];
  #pragma unroll
  for (int i = 0; i < SI; ++i) {
    int idx = base + i;
    if (idx < n) out[idx] = bo + texcl + loc[i];
  }
}

// ---------------- pipeline kernels ----------------

// classification: occ byte, 64-way-replicated fine histogram (lo>>6), per-block tri sums.
// Replication keeps same-address atomic contention ~15 ops/addr (R6's single copy was
// ~960 ops/addr -> 526us of serialized memory-side RMWs).
__global__ void k_classify(const int* __restrict__ tet, const float* __restrict__ sdf,
                           unsigned* __restrict__ fineCnt64, unsigned char* __restrict__ occb,
                           unsigned* __restrict__ bs, int F, int FB, int PF) {
  int f = blockIdx.x * TB + threadIdx.x;
  unsigned pk = 0;
  unsigned rep = ((unsigned)threadIdx.x ^ (unsigned)blockIdx.x) & 63u;
  unsigned rbase = rep * (unsigned)PF;
  if (f < F) {
    int4 q = reinterpret_cast<const int4*>(tet)[f];
    int v[4] = {q.x, q.y, q.z, q.w};
    int oc[4];
    #pragma unroll
    for (int i = 0; i < 4; ++i) oc[i] = sdf[v[i]] > 0.0f;
    int tix = oc[0] | (oc[1] << 1) | (oc[2] << 2) | (oc[3] << 3);
    occb[f] = (unsigned char)tix;
    int nt = d_NT[tix];
    pk = (nt == 1 ? 1u : 0u) | (nt == 2 ? 0x10000u : 0u);
    if (nt > 0) {
      #pragma unroll
      for (int e = 0; e < 6; ++e) {
        int ai = d_EA[e], bi = d_EB[e];
        if (oc[ai] != oc[bi]) {
          int a = v[ai], b = v[bi];
          int lo = a < b ? a : b;
          atomicAdd(&fineCnt64[rbase + (unsigned)(lo >> 6)], 1u);
        }
      }
    }
  }
  __shared__ unsigned sh[TB];
  sh[threadIdx.x] = pk; __syncthreads();
  for (int st = TB/2; st > 0; st >>= 1) {
    if (threadIdx.x < st) sh[threadIdx.x] += sh[threadIdx.x + st];
    __syncthreads();
  }
  if (threadIdx.x == 0) {
    unsigned t = sh[0];
    bs[blockIdx.x] = t & 0xFFFFu;
    bs[FB + blockIdx.x] = t >> 16;
  }
}

// fold the 64 histogram replicas into fineCnt (coalesced per-replica passes)
__global__ void k_redsum(const unsigned* __restrict__ fineCnt64, unsigned* __restrict__ fineCnt,
                         int PF) {
  int i = blockIdx.x * TB + threadIdx.x;
  if (i >= PF) return;
  unsigned s = 0;
  for (int r = 0; r < 64; ++r) s += fineCnt64[(unsigned)r * (unsigned)PF + (unsigned)i];
  fineCnt[i] = s;
}

// init cursors after fine scan
__global__ void k_init(const unsigned* __restrict__ fineOff, unsigned* __restrict__ finecur,
                       unsigned* __restrict__ ccur, int PF, int PC) {
  int i = blockIdx.x * TB + threadIdx.x;
  if (i < PF) finecur[i] = fineOff[i];
  if (i < 64) ccur[i] = (i < PC) ? fineOff[i * 128] : 0u;
}

// pass 1: LDS-binned scatter into <=37 coarse partitions (lo>>13); coalesced run flushes
#define P1MAX 1536
__global__ void k_scat1(const int* __restrict__ tet, const unsigned char* __restrict__ occb,
                        unsigned* __restrict__ ccur, unsigned* __restrict__ streamA,
                        int F, unsigned capA) {
  __shared__ unsigned hist[64], offb[64], cur[64], gb[64];
  __shared__ unsigned sbuf[P1MAX];
  __shared__ unsigned char sfb[P1MAX];
  int t = threadIdx.x;
  if (t < 64) { hist[t] = 0; cur[t] = 0; }
  __syncthreads();
  int f = blockIdx.x * TB + t;
  unsigned ev[6]; unsigned char fv[6]; unsigned vm = 0;
  #pragma unroll
  for (int e = 0; e < 6; ++e) { ev[e] = 0; fv[e] = 0; }
  if (f < F) {
    int tix = occb[f];
    if (tix != 0 && tix != 15) {
      int4 q = reinterpret_cast<const int4*>(tet)[f];
      int v[4] = {q.x, q.y, q.z, q.w};
      #pragma unroll
      for (int e = 0; e < 6; ++e) {
        int ai = d_EA[e], bi = d_EB[e];
        if (((tix >> ai) & 1) != ((tix >> bi) & 1)) {
          int a = v[ai], b = v[bi];
          int lo = a < b ? a : b;
          int hi = a < b ? b : a;
          ev[e] = ((unsigned)(lo & 8191) << 19) | (unsigned)hi;
          fv[e] = (unsigned char)(lo >> 13);
          atomicAdd(&hist[lo >> 13], 1u);
          vm |= 1u << e;
        }
      }
    }
  }
  __syncthreads();
  if (t == 0) { unsigned s = 0; for (int i = 0; i < 64; ++i) { offb[i] = s; s += hist[i]; } }
  __syncthreads();
  #pragma unroll
  for (int e = 0; e < 6; ++e) if ((vm >> e) & 1) {
    unsigned fb = fv[e];
    unsigned slot = offb[fb] + atomicAdd(&cur[fb], 1u);
    if (slot < P1MAX) { sbuf[slot] = ev[e]; sfb[slot] = (unsigned char)fb; }
  }
  if (t < 64 && hist[t] > 0) gb[t] = atomicAdd(&ccur[t], hist[t]);
  __syncthreads();
  unsigned total = offb[63] + hist[63];
  if (total > P1MAX) total = P1MAX;
  for (unsigned i = t; i < total; i += TB) {
    unsigned fb = sfb[i];
    unsigned pos = gb[fb] + (i - offb[fb]);
    if (pos < capA) streamA[pos] = sbuf[i];
  }
}

// pass 2: repartition coarse -> fine (128 bins of 64 lo each); coalesced run flushes.
// NPB=64: worst coarse partition (~242K entries, lo-min skew 2x at 0) -> chunk <= ~3790 < P2CAP.
#define NPB 64
#define P2CAP 4096
__global__ void k_repart(const unsigned* __restrict__ fineOff, const unsigned* __restrict__ streamA,
                         unsigned* __restrict__ finecur, unsigned* __restrict__ streamB,
                         int PF, unsigned capB) {
  __shared__ unsigned hist[128], offb[128], cur[128], gb[128];
  __shared__ unsigned sorted[P2CAP];
  __shared__ unsigned char sfb[P2CAP];
  int t = threadIdx.x;
  int pc = blockIdx.x / NPB;
  int ib = blockIdx.x % NPB;
  for (int i = t; i < 128; i += TB) { hist[i] = 0; cur[i] = 0; }
  __syncthreads();
  int fs = pc * 128;
  int fe = fs + 128; if (fe > PF) fe = PF;
  unsigned base = fineOff[fs], end = fineOff[fe];
  unsigned cc = end - base;
  unsigned chunk = (cc + NPB - 1) / NPB;
  if (chunk > P2CAP) chunk = P2CAP;   // safety (should never trigger at NPB=64)
  unsigned s = base + (unsigned)ib * chunk;
  if (s > end) s = end;
  unsigned e_ = s + chunk; if (e_ > end) e_ = end;
  unsigned ev[16]; unsigned char fv[16];
  #pragma unroll
  for (int j = 0; j < 16; ++j) {
    unsigned idx = s + (unsigned)(j * TB) + (unsigned)t;
    bool ok = idx < e_;
    unsigned eV = 0;
    if (ok) { eV = streamA[idx]; atomicAdd(&hist[eV >> 25], 1u); }
    ev[j] = eV; fv[j] = ok ? (unsigned char)(eV >> 25) : (unsigned char)255;
  }
  __syncthreads();
  if (t == 0) { unsigned ss = 0; for (int i = 0; i < 128; ++i) { offb[i] = ss; ss += hist[i]; } }
  __syncthreads();
  #pragma unroll
  for (int j = 0; j < 16; ++j) if (fv[j] != 255) {
    unsigned fb = fv[j];
    unsigned slot = offb[fb] + atomicAdd(&cur[fb], 1u);
    if (slot < P2CAP) { sorted[slot] = ev[j] & 0x1FFFFFFu; sfb[slot] = fv[j]; }
  }
  if (t < 128 && hist[t] > 0) gb[t] = atomicAdd(&finecur[fs + t], hist[t]);
  __syncthreads();
  unsigned total = offb[127] + hist[127];
  if (total > P2CAP) total = P2CAP;
  for (unsigned i = t; i < total; i += TB) {
    unsigned fb = sfb[i];
    unsigned pos = gb[fb] + (i - offb[fb]);
    if (pos < capB) streamB[pos] = sorted[i];
  }
}

// one 512-thread block per fine partition (64 lo); 8 waves each sort+dedupe one 8-lo bucket.
// PCAP=2560: partition 0 expects ~1920 entries (lo-min skew), +14 sigma margin.
#define PCAP 2560
#define CAP 512
__global__ void __launch_bounds__(512) k_sortdd(
    const unsigned* __restrict__ fineOff, unsigned* __restrict__ streamB,
    unsigned* __restrict__ ucnt, unsigned* __restrict__ ucC,
    unsigned* __restrict__ ustart, int N) {
  __shared__ unsigned sSt[PCAP];
  __shared__ unsigned sA[8][CAP];
  __shared__ unsigned sD[8][CAP];
  __shared__ unsigned sUc[8];
  int t = threadIdx.x;
  int w = t >> 6, lane = t & 63;
  int fp = blockIdx.x;
  unsigned base = fineOff[fp];
  unsigned n = fineOff[fp + 1] - base;
  if (n > PCAP) n = PCAP;   // safety (should never trigger at PCAP=2560)
  for (unsigned k = t; k < n; k += 512) sSt[k] = streamB[base + k];
  __syncthreads();
  // filter this wave's 8-lo bucket ((e>>22)&7 == w) into sA[w]
  unsigned nw = 0;
  for (unsigned c = 0; c < n; c += 64) {
    unsigned j = c + (unsigned)lane; bool m = false; unsigned e = 0;
    if (j < n) { e = sSt[j]; m = ((e >> 22) & 7u) == (unsigned)w; }
    unsigned long long bal = __ballot((int)m);
    if (m) {
      unsigned pos = nw + (unsigned)__popcll(bal & ((1ull << lane) - 1ull));
      if (pos < CAP) sA[w][pos] = e;
    }
    nw += (unsigned)__popcll(bal);
  }
  if (nw > CAP) nw = CAP;   // safety
  wave_sync_lds();
  // rank-sort sA[w][0..nw) -> sD[w]
  for (unsigned k = lane; k < nw; k += 64) {
    unsigned val = sA[w][k];
    unsigned r = 0;
    for (unsigned j = 0; j < nw; ++j) {
      unsigned x = sA[w][j];
      r += (x < val) || (x == val && j < k);
    }
    sD[w][r] = val;
  }
  wave_sync_lds();
  // dedupe sD -> sA
  unsigned ub = 0;
  for (unsigned c = 0; c < nw; c += 64) {
    unsigned k = c + (unsigned)lane;
    bool act = k < nw;
    unsigned val = act ? sD[w][k] : 0u;
    bool flag = act && (k == 0 || val != sD[w][k - 1]);
    unsigned long long m2 = __ballot((int)flag);
    if (flag) {
      unsigned pos = ub + (unsigned)__popcll(m2 & ((1ull << lane) - 1ull));
      sA[w][pos] = val;
    }
    ub += (unsigned)__popcll(m2);
  }
  wave_sync_lds();
  if (lane == 0) sUc[w] = ub;
  __syncthreads();
  unsigned pre = 0;
  for (int i = 0; i < w; ++i) pre += sUc[i];
  unsigned ust = base + pre;
  // write packed uniques (idx<<25 | lo6<<19 | hi) back into streamB (reads were from sSt)
  for (unsigned k = lane; k < ub; k += 64) {
    unsigned e = sA[w][k];
    unsigned j = k;
    while (j > 0 && (sA[w][j - 1] >> 19) == (e >> 19)) --j;
    streamB[ust + k] = ((k - j) << 25) | e;
  }
  // per-lo unique counts
  if (lane < 8) {
    unsigned c = 0;
    for (unsigned j = 0; j < ub; ++j) c += ((sA[w][j] >> 19) & 7u) == (unsigned)lane;
    int lo = fp * 64 + w * 8 + (int)lane;
    if (lo < N) ucnt[lo] = c;
  }
  int cb = fp * 8 + w;
  if (lane == 0) { ucC[cb] = ub; ustart[cb] = ust; }
}

// verts + uniq table (uniq table lives in streamA, dead after repart)
__global__ void k_verts(const unsigned* __restrict__ ustart, const unsigned* __restrict__ ucC,
                        const unsigned* __restrict__ uoff, const unsigned* __restrict__ streamB,
                        unsigned* __restrict__ uniqA, const float* __restrict__ pos,
                        const float* __restrict__ sdf, float* __restrict__ out,
                        int NCB, int N, unsigned out_cap) {
  int w = threadIdx.x >> 6, lane = threadIdx.x & 63;
  int cb = blockIdx.x * 4 + w;
  if (cb >= NCB) return;
  unsigned u = ucC[cb];
  if (u == 0) return;
  unsigned us = ustart[cb];
  unsigned lobase = (unsigned)(cb >> 3) * 64u;
  unsigned M = uoff[N];
  for (unsigned k = lane; k < u; k += 64) {
    unsigned e = streamB[us + k];
    unsigned hi = e & 0x7FFFFu;
    unsigned lo = lobase + ((e >> 19) & 63u);
    unsigned idx = e >> 25;
    if (lo >= (unsigned)N || hi >= (unsigned)N) continue;
    unsigned r = uoff[lo] + idx;
    if (r >= M) continue;
    size_t ro = (size_t)3 * r;
    if (ro + 3 > (size_t)out_cap) continue;
    uniqA[r] = hi;
    float a = sdf[lo], b = sdf[hi];
    float d = a - b;
    float w0 = -b / d;
    float w1 = a / d;
    out[ro + 0] = pos[3 * (size_t)lo + 0] * w0 + pos[3 * (size_t)hi + 0] * w1;
    out[ro + 1] = pos[3 * (size_t)lo + 1] * w0 + pos[3 * (size_t)hi + 1] * w1;
    out[ro + 2] = pos[3 * (size_t)lo + 2] * w0 + pos[3 * (size_t)hi + 2] * w1;
  }
}

// faces: block-local scan + per-block offsets from C over [bs1|bs2]; bounded uniq search
__global__ void k_faces(const int* __restrict__ tet, const unsigned char* __restrict__ occb,
                        const unsigned* __restrict__ uoff, const unsigned* __restrict__ uniqA,
                        const unsigned* __restrict__ C, float* __restrict__ out,
                        int F, int FB, int N, unsigned out_cap) {
  int f = blockIdx.x * TB + threadIdx.x;
  int tix = (f < F) ? (int)occb[f] : 0;
  int nt = d_NT[tix];
  unsigned pk = (nt == 1 ? 1u : 0u) | (nt == 2 ? 0x10000u : 0u);
  __shared__ unsigned sh[TB];
  int t = threadIdx.x;
  sh[t] = pk; __syncthreads();
  for (int o = 1; o < TB; o <<= 1) {
    unsigned v = (t >= o) ? sh[t - o] : 0u;
    __syncthreads();
    sh[t] += v;
    __syncthreads();
  }
  unsigned excl = sh[t] - pk;
  if (f >= F || nt == 0) return;
  unsigned C1b = C[blockIdx.x];
  unsigned T1 = C[FB];
  unsigned C2b = C[FB + blockIdx.x] - T1;
  unsigned M = uoff[N];
  int4 q = reinterpret_cast<const int4*>(tet)[f];
  int v[4] = {q.x, q.y, q.z, q.w};
  int rank[6];
  #pragma unroll
  for (int e = 0; e < 6; ++e) {
    int ai = d_EA[e], bi = d_EB[e];
    int oa = (tix >> ai) & 1, ob = (tix >> bi) & 1;
    if (oa != ob) {
      int a = v[ai], b = v[bi];
      int lo = a < b ? a : b;
      int hi = a < b ? b : a;
      unsigned ubase = uoff[lo];
      unsigned len = uoff[lo + 1] - ubase;   // bounded search — no hang possible
      unsigned rk = ubase;
      for (unsigned j = 0; j < len; ++j) {
        if (uniqA[ubase + j] == (unsigned)hi) { rk = ubase + j; break; }
      }
      rank[e] = (int)rk;
    } else {
      rank[e] = -1;
    }
  }
  const int* tt = d_TRI[tix];
  if (nt == 1) {
    unsigned r = C1b + (excl & 0xFFFFu);
    size_t o = (size_t)3 * M + (size_t)3 * r;
    if (o + 3 <= (size_t)out_cap) {
      out[o + 0] = (float)rank[tt[0]];
      out[o + 1] = (float)rank[tt[1]];
      out[o + 2] = (float)rank[tt[2]];
    }
  } else {
    unsigned r0 = T1 + 2u * (C2b + (excl >> 16));
    size_t o = (size_t)3 * M + (size_t)3 * r0;
    if (o + 6 <= (size_t)out_cap) {
      #pragma unroll
      for (int c = 0; c < 6; ++c) out[o + c] = (float)rank[tt[c]];
    }
  }
}

// ---------------- host launcher ----------------
static void run_scan(const unsigned* in, unsigned* out, int n,
                     unsigned* bsum, unsigned* boff, hipStream_t s) {
  int B = (n + STILE - 1) / STILE;
  k_scan_partial<<<B, SB, 0, s>>>(in, bsum, n);
  k_scan_mid<<<1, SB, 0, s>>>(bsum, boff, B, out + n);
  k_scan_final<<<B, SB, 0, s>>>(in, boff, out, n);
}

extern "C" void kernel_launch(void* const* d_in, const int* in_sizes, int n_in,
                              void* d_out, int out_size, void* d_ws, size_t ws_size,
                              hipStream_t stream) {
  const float* pos = (const float*)d_in[0];
  const float* sdf = (const float*)d_in[1];
  const int* tet = (const int*)d_in[2];
  int N = in_sizes[1];
  int F = in_sizes[2] / 4;
  float* out = (float*)d_out;

  char* w = (char*)d_ws;
  size_t o = 0;
  auto take = [&](size_t bytes) -> char* {
    char* p = w + o;
    o = (o + bytes + 255) & ~(size_t)255;
    return p;
  };
  int FB = (F + TB - 1) / TB;
  int PF = (N + 63) / 64;          // fine partitions (64 lo each)
  int PC = (PF + 127) / 128;       // coarse partitions (8192 lo each)
  int NCB = PF * 8;                // 8-lo buckets
  unsigned capS = (unsigned)(4 * F);   // stream capacity in entries

  unsigned* fineCnt64 = (unsigned*)take((size_t)64 * PF * 4);  // 64 replicas (contention fix)
  unsigned* fineCnt = (unsigned*)take((size_t)(PF + 1) * 4);
  unsigned* fineOff = (unsigned*)take((size_t)(PF + 1) * 4);
  unsigned* finecur = (unsigned*)take((size_t)(PF + 1) * 4);
  unsigned* ccur    = (unsigned*)take(64 * 4);
  unsigned* ucnt    = (unsigned*)take((size_t)(N + 1) * 4);
  unsigned* uoff    = (unsigned*)take((size_t)(N + 1) * 4);
  unsigned* ucC     = (unsigned*)take((size_t)NCB * 4);
  unsigned* ustart  = (unsigned*)take((size_t)NCB * 4);
  unsigned* bs      = (unsigned*)take((size_t)2 * FB * 4);
  unsigned* C       = (unsigned*)take(((size_t)2 * FB + 1) * 4);
  unsigned char* occb = (unsigned char*)take((size_t)F);
  unsigned* streamA = (unsigned*)take((size_t)capS * 4);  // coarse stream, later uniq table
  unsigned* streamB = (unsigned*)take((size_t)capS * 4);  // fine stream, later packed uniques
  unsigned* bsum    = (unsigned*)take(4096 * 4);
  unsigned* boff    = (unsigned*)take(4096 * 4);

  // 1) zero replicated fine histogram
  hipMemsetAsync(fineCnt64, 0, (size_t)64 * PF * 4, stream);
  // 2) classify (atomics spread over 64 replicas)
  k_classify<<<FB, TB, 0, stream>>>(tet, sdf, fineCnt64, occb, bs, F, FB, PF);
  // 2b) fold replicas
  k_redsum<<<(PF + TB - 1) / TB, TB, 0, stream>>>(fineCnt64, fineCnt, PF);
  // 3) fine offsets
  run_scan(fineCnt, fineOff, PF, bsum, boff, stream);
  // 4) cursors
  k_init<<<(PF + TB - 1) / TB, TB, 0, stream>>>(fineOff, finecur, ccur, PF, PC);
  // 5) coarse binned scatter
  k_scat1<<<FB, TB, 0, stream>>>(tet, occb, ccur, streamA, F, capS);
  // 6) repartition coarse -> fine
  k_repart<<<PC * NPB, TB, 0, stream>>>(fineOff, streamA, finecur, streamB, PF, capS);
  // 7) per-fine-partition sort + dedupe (uniques back into streamB)
  k_sortdd<<<PF, 512, 0, stream>>>(fineOff, streamB, ucnt, ucC, ustart, N);
  // 8) unique offsets (global lex ranks); uoff[N] = M
  run_scan(ucnt, uoff, N, bsum, boff, stream);
  // 9) verts + uniq table (into streamA)
  k_verts<<<(NCB + 3) / 4, TB, 0, stream>>>(ustart, ucC, uoff, streamB, streamA,
                                            pos, sdf, out, NCB, N, (unsigned)out_size);
  // 10) face row offsets
  run_scan(bs, C, 2 * FB, bsum, boff, stream);
  // 11) faces
  k_faces<<<FB, TB, 0, stream>>>(tet, occb, uoff, streamA, C, out, F, FB, N, (unsigned)out_size);
}